// Round 7
// baseline (208.190 us; speedup 1.0000x reference)
//
#include <hip/hip_runtime.h>
#include <hip/hip_bf16.h>

// CalcSpixelFeats R7.
// R6 post-mortem: prep WRITE_SIZE 78MB (ideal 28) — bucket scatter wrote
// 10x4B to 10 separate planes at random pos = line-granularity write
// amplification + partial-line RMW. Fix: ONE 128B record per pixel
// [bf16 feat x32 (64B) | w[9]+pad (64B)] -> 2 full lines, zero amplification,
// and pfT/transpose kernel removed entirely. Gather streams records
// SEQUENTIALLY per bucket (no pixel indirection, no dependent chain).
// Overflow past cap -> rare global fp32 atomics into ovf[B*K][33].

#define CCH  32         // channels, fixed by problem
#define TPB  256        // prep block
#define GTPB 512        // gather block: 16 ch-pair lanes x 32 pixel groups
#define CAPC 384        // bucket capacity (mean 256, sd 16 -> +8 sigma)
#define RECW 32         // record width in dwords (128 B)

__device__ __forceinline__ unsigned pack_bf16(float a, float b) {
    unsigned ua = __float_as_uint(a);
    unsigned ub = __float_as_uint(b);
    ua = (ua + 0x7FFFu + ((ua >> 16) & 1u)) >> 16;   // RNE
    ub = (ub + 0x7FFFu + ((ub >> 16) & 1u)) >> 16;
    return ua | (ub << 16);
}

__global__ __launch_bounds__(TPB) void spx_prep_kernel(
    const float* __restrict__ pf,      // [B][C][P]
    const float* __restrict__ assoc,   // [B][9][P]
    const int*   __restrict__ idxmap,  // [B][P]
    const int*   __restrict__ nw_p,
    const int*   __restrict__ nh_p,
    int*         __restrict__ cnt,     // [B*K]
    unsigned*    __restrict__ recs,    // [B*K][cap][RECW]
    float*       __restrict__ ovf,     // [B*K][33] overflow accumulator
    int P, int K, int cap, int cpb)
{
    const int b = blockIdx.x / cpb;
    const int p = (blockIdx.x - b * cpb) * TPB + threadIdx.x;

    const float* pf_b = pf + (size_t)b * CCH * P;
    float f[CCH];
#pragma unroll
    for (int c = 0; c < CCH; ++c) f[c] = pf_b[(size_t)c * P + p];  // coalesced

    unsigned u[16];
#pragma unroll
    for (int c2 = 0; c2 < 16; ++c2) u[c2] = pack_bf16(f[2*c2], f[2*c2+1]);

    const float* as_b = assoc + (size_t)b * 9 * P;
    float wv[9];
#pragma unroll
    for (int j = 0; j < 9; ++j) wv[j] = as_b[(size_t)j * P + p];   // coalesced

    const int idx = idxmap[(size_t)b * P + p];
    const int pos = atomicAdd(&cnt[b * K + idx], 1);

    if (pos < cap) {
        uint4* dst = (uint4*)(recs +
            ((size_t)(b * K + idx) * cap + pos) * RECW);
        dst[0] = make_uint4(u[0],  u[1],  u[2],  u[3]);
        dst[1] = make_uint4(u[4],  u[5],  u[6],  u[7]);
        dst[2] = make_uint4(u[8],  u[9],  u[10], u[11]);
        dst[3] = make_uint4(u[12], u[13], u[14], u[15]);
        dst[4] = make_uint4(__float_as_uint(wv[0]), __float_as_uint(wv[1]),
                            __float_as_uint(wv[2]), __float_as_uint(wv[3]));
        dst[5] = make_uint4(__float_as_uint(wv[4]), __float_as_uint(wv[5]),
                            __float_as_uint(wv[6]), __float_as_uint(wv[7]));
        dst[6] = make_uint4(__float_as_uint(wv[8]), 0u, 0u, 0u);
        dst[7] = make_uint4(0u, 0u, 0u, 0u);
    } else {
        // rare overflow: scatter directly with global fp atomics (native)
        const int nw = nw_p[0], nh = nh_p[0];
        const int iy = idx / nw, ixx = idx - (idx / nw) * nw;
#pragma unroll
        for (int j = 0; j < 9; ++j) {
            const int ty = iy + j / 3 - 1, tx = ixx + j % 3 - 1;
            if (tx >= 0 && tx < nw && ty >= 0 && ty < nh) {
                float* o = ovf + (size_t)(b * K + ty * nw + tx) * (CCH + 1);
#pragma unroll
                for (int c = 0; c < CCH; ++c)
                    unsafeAtomicAdd(&o[c], wv[j] * f[c]);
                unsafeAtomicAdd(&o[CCH], wv[j]);
            }
        }
    }
}

// Block owns output bin (b,k). Streams 9 neighbor buckets sequentially.
__global__ __launch_bounds__(GTPB) void spx_gather_kernel(
    const unsigned* __restrict__ recs,    // [B*K][cap][RECW]
    const int*      __restrict__ cnt,     // [B*K]
    const float*    __restrict__ ovf,     // [B*K][33]
    const int*      __restrict__ nw_p,
    const int*      __restrict__ nh_p,
    float*          __restrict__ out,     // [B][C][K]
    int P, int K, int cap)
{
    __shared__ int   jcnt[9], jsrc[9];
    __shared__ float red[32][CCH + 1];

    const int b   = blockIdx.x / K;
    const int k   = blockIdx.x - b * K;
    const int tid = threadIdx.x;
    const int nw  = nw_p[0];
    const int nh  = nh_p[0];
    const int ky  = k / nw;
    const int kx  = k - ky * nw;

    if (tid < 9) {
        const int dy = tid / 3 - 1, dx = tid % 3 - 1;
        const int sy = ky - dy, sx = kx - dx;      // source base bin
        const bool v = (sx >= 0) & (sx < nw) & (sy >= 0) & (sy < nh);
        const int src = v ? (b * K + sy * nw + sx) : 0;
        int c = v ? cnt[src] : 0;
        if (c > cap) c = cap;
        jcnt[tid] = c;
        jsrc[tid] = src;
    }
    __syncthreads();

    const int ch2 = tid & 15;      // channel pair lane
    const int q   = tid >> 4;      // pixel group 0..31

    float a0 = 0.f, a1 = 0.f, wacc = 0.f;
#pragma unroll
    for (int j = 0; j < 9; ++j) {
        const int c = jcnt[j];
        const unsigned* rb = recs + (size_t)jsrc[j] * cap * RECW;
        for (int i = q; i < c; i += 32) {
            const unsigned* r = rb + (size_t)i * RECW;
            const float w = __uint_as_float(r[16 + j]);  // broadcast in group
            const unsigned u = r[ch2];                   // 64B line per group
            a0   += w * __uint_as_float(u << 16);
            a1   += w * __uint_as_float(u & 0xFFFF0000u);
            wacc += w;
        }
    }

    red[q][2 * ch2]     = a0;
    red[q][2 * ch2 + 1] = a1;
    if (ch2 == 0) red[q][CCH] = wacc;
    __syncthreads();

    if (tid < CCH + 1) {
        float F = 0.f;
#pragma unroll
        for (int r = 0; r < 32; ++r) F += red[r][tid];
        F += ovf[(size_t)(b * K + k) * (CCH + 1) + tid];  // rare overflow
        red[0][tid] = F;   // red[0][0..31] = fsum, red[0][32] = wsum
    }
    __syncthreads();

    if (tid < CCH) {
        const float W   = red[0][CCH];
        const float res = (W > 1e-16f) ? (red[0][tid] / W) : 0.f;
        out[((size_t)b * CCH + tid) * K + k] = res;
    }
}

extern "C" void kernel_launch(void* const* d_in, const int* in_sizes, int n_in,
                              void* d_out, int out_size, void* d_ws, size_t ws_size,
                              hipStream_t stream) {
    const float* pf     = (const float*)d_in[0];
    const float* assoc  = (const float*)d_in[1];
    const int*   idxmap = (const int*)d_in[2];
    const int*   nw_p   = (const int*)d_in[3];
    const int*   nh_p   = (const int*)d_in[4];
    float* out = (float*)d_out;

    const int BP = in_sizes[2];          // B*P = 262144
    const int B  = 4;                    // fixed by reference setup
    const int P  = BP / B;               // 65536
    const int K  = out_size / (B * CCH); // 256

    // workspace: cnt [B*K int] | ovf [B*K*33 f32] | recs [B*K][cap][128B]
    const size_t cnt_bytes = (size_t)B * K * sizeof(int);
    const size_t ovf_bytes = (size_t)B * K * (CCH + 1) * sizeof(float);
    int*      cnt  = (int*)d_ws;
    float*    ovf  = (float*)((char*)d_ws + cnt_bytes);
    unsigned* recs = (unsigned*)((char*)d_ws + cnt_bytes + ovf_bytes);

    size_t avail = (ws_size > cnt_bytes + ovf_bytes)
                       ? (ws_size - cnt_bytes - ovf_bytes) : 0;
    int cap = (int)(avail / ((size_t)B * K * RECW * sizeof(unsigned)));
    if (cap > CAPC) cap = CAPC;
    if (cap < 1) cap = 1;

    hipMemsetAsync(cnt, 0, cnt_bytes + ovf_bytes, stream);  // cnt + ovf = 0

    const int cpb = P / TPB;             // 256
    spx_prep_kernel<<<B * cpb, TPB, 0, stream>>>(
        pf, assoc, idxmap, nw_p, nh_p, cnt, recs, ovf, P, K, cap, cpb);

    spx_gather_kernel<<<B * K, GTPB, 0, stream>>>(
        recs, cnt, ovf, nw_p, nh_p, out, P, K, cap);
}

// Round 8
// 138.244 us; speedup vs baseline: 1.5060x; 1.5060x over previous
//
#include <hip/hip_runtime.h>
#include <hip/hip_bf16.h>

// CalcSpixelFeats R8.
// R7 post-mortem: records write clean (38MB) but prep SLOWER at 0.6TB/s, 5%
// HBM. Wave-chain arithmetic says ~5us; measured 96us. Common term across
// R5(90)/R6(72)/R7(96): 262K RETURNING global atomics to 1024 hot counters
// (~1 reservation/cy at the coherence point ~= 110us). R8: block-aggregated
// reservations. 512-thr block owns 1024 px: LDS int histogram (ds_add_rtn)
// -> local rank; ONE global atomicAdd per (block,bin) = 65K atomics (4x cut).
// Record format + gather identical to R7.

#define CCH  32         // channels, fixed by problem
#define TPB  512        // prep block threads
#define PPB  1024       // pixels per prep block (2 per thread)
#define GTPB 512        // gather block: 16 ch-pair lanes x 32 pixel groups
#define CAPC 384        // bucket capacity (mean 256, sd 16 -> +8 sigma)
#define RECW 32         // record width in dwords (128 B)
#define KMAX 256

__device__ __forceinline__ unsigned pack_bf16(float a, float b) {
    unsigned ua = __float_as_uint(a);
    unsigned ub = __float_as_uint(b);
    ua = (ua + 0x7FFFu + ((ua >> 16) & 1u)) >> 16;   // RNE
    ub = (ub + 0x7FFFu + ((ub >> 16) & 1u)) >> 16;
    return ua | (ub << 16);
}

__global__ __launch_bounds__(TPB) void spx_prep_kernel(
    const float* __restrict__ pf,      // [B][C][P]
    const float* __restrict__ assoc,   // [B][9][P]
    const int*   __restrict__ idxmap,  // [B][P]
    const int*   __restrict__ nw_p,
    const int*   __restrict__ nh_p,
    int*         __restrict__ cnt,     // [B*K]
    unsigned*    __restrict__ recs,    // [B*K][cap][RECW]
    float*       __restrict__ ovf,     // [B*K][33] overflow accumulator
    int P, int K, int cap, int bpb)    // bpb = P / PPB
{
    __shared__ int hist[KMAX];         // per-block bin counts
    __shared__ int bases[KMAX];        // reserved global base per bin

    const int b   = blockIdx.x / bpb;
    const int blk = blockIdx.x - b * bpb;
    const int tid = threadIdx.x;
    const int p0  = blk * PPB;         // within batch

    for (int i = tid; i < K; i += TPB) hist[i] = 0;
    __syncthreads();

    const int pA = p0 + tid;
    const int pB = p0 + TPB + tid;
    const int*   ix_b = idxmap + (size_t)b * P;
    const float* pf_b = pf     + (size_t)b * CCH * P;
    const float* as_b = assoc  + (size_t)b * 9 * P;

    // local ranks via native LDS int atomics
    const int idxA  = ix_b[pA];
    const int idxB  = ix_b[pB];
    const int rankA = atomicAdd(&hist[idxA], 1);
    const int rankB = atomicAdd(&hist[idxB], 1);

    // bulk loads (independent of the reservation phase; stay in flight)
    unsigned uA[16], uB[16];
#pragma unroll
    for (int c2 = 0; c2 < 16; ++c2) {
        const float a0 = pf_b[(size_t)(2*c2  ) * P + pA];
        const float a1 = pf_b[(size_t)(2*c2+1) * P + pA];
        const float b0 = pf_b[(size_t)(2*c2  ) * P + pB];
        const float b1 = pf_b[(size_t)(2*c2+1) * P + pB];
        uA[c2] = pack_bf16(a0, a1);
        uB[c2] = pack_bf16(b0, b1);
    }
    float wA[9], wB[9];
#pragma unroll
    for (int j = 0; j < 9; ++j) {
        wA[j] = as_b[(size_t)j * P + pA];
        wB[j] = as_b[(size_t)j * P + pB];
    }

    __syncthreads();
    // ONE returning global atomic per (block, bin): 256 lanes reserve runs
    for (int i = tid; i < K; i += TPB)
        bases[i] = atomicAdd(&cnt[b * K + i], hist[i]);
    __syncthreads();

    const int nw = nw_p[0], nh = nh_p[0];

#pragma unroll
    for (int px = 0; px < 2; ++px) {
        const int idx  = px ? idxB : idxA;
        const int rank = px ? rankB : rankA;
        const unsigned* u = px ? uB : uA;
        const float*    w = px ? wB : wA;
        const int pos = bases[idx] + rank;

        if (pos < cap) {
            uint4* dst = (uint4*)(recs +
                ((size_t)(b * K + idx) * cap + pos) * RECW);
            dst[0] = make_uint4(u[0],  u[1],  u[2],  u[3]);
            dst[1] = make_uint4(u[4],  u[5],  u[6],  u[7]);
            dst[2] = make_uint4(u[8],  u[9],  u[10], u[11]);
            dst[3] = make_uint4(u[12], u[13], u[14], u[15]);
            dst[4] = make_uint4(__float_as_uint(w[0]), __float_as_uint(w[1]),
                                __float_as_uint(w[2]), __float_as_uint(w[3]));
            dst[5] = make_uint4(__float_as_uint(w[4]), __float_as_uint(w[5]),
                                __float_as_uint(w[6]), __float_as_uint(w[7]));
            dst[6] = make_uint4(__float_as_uint(w[8]), 0u, 0u, 0u);
            dst[7] = make_uint4(0u, 0u, 0u, 0u);
        } else {
            // rare overflow: direct scatter with native global fp atomics.
            // bf16-unpacked feats, consistent with the record path.
            const int iy = idx / nw, ixx = idx - (idx / nw) * nw;
#pragma unroll
            for (int j = 0; j < 9; ++j) {
                const int ty = iy + j / 3 - 1, tx = ixx + j % 3 - 1;
                if (tx >= 0 && tx < nw && ty >= 0 && ty < nh) {
                    float* o = ovf + (size_t)(b * K + ty * nw + tx) * (CCH + 1);
#pragma unroll
                    for (int c2 = 0; c2 < 16; ++c2) {
                        const float f0 = __uint_as_float(u[c2] << 16);
                        const float f1 = __uint_as_float(u[c2] & 0xFFFF0000u);
                        unsafeAtomicAdd(&o[2*c2],     w[j] * f0);
                        unsafeAtomicAdd(&o[2*c2 + 1], w[j] * f1);
                    }
                    unsafeAtomicAdd(&o[CCH], w[j]);
                }
            }
        }
    }
}

// Block owns output bin (b,k). Streams 9 neighbor buckets sequentially.
__global__ __launch_bounds__(GTPB) void spx_gather_kernel(
    const unsigned* __restrict__ recs,    // [B*K][cap][RECW]
    const int*      __restrict__ cnt,     // [B*K]
    const float*    __restrict__ ovf,     // [B*K][33]
    const int*      __restrict__ nw_p,
    const int*      __restrict__ nh_p,
    float*          __restrict__ out,     // [B][C][K]
    int P, int K, int cap)
{
    __shared__ int   jcnt[9], jsrc[9];
    __shared__ float red[32][CCH + 1];

    const int b   = blockIdx.x / K;
    const int k   = blockIdx.x - b * K;
    const int tid = threadIdx.x;
    const int nw  = nw_p[0];
    const int nh  = nh_p[0];
    const int ky  = k / nw;
    const int kx  = k - ky * nw;

    if (tid < 9) {
        const int dy = tid / 3 - 1, dx = tid % 3 - 1;
        const int sy = ky - dy, sx = kx - dx;      // source base bin
        const bool v = (sx >= 0) & (sx < nw) & (sy >= 0) & (sy < nh);
        const int src = v ? (b * K + sy * nw + sx) : 0;
        int c = v ? cnt[src] : 0;
        if (c > cap) c = cap;
        jcnt[tid] = c;
        jsrc[tid] = src;
    }
    __syncthreads();

    const int ch2 = tid & 15;      // channel pair lane
    const int q   = tid >> 4;      // pixel group 0..31

    float a0 = 0.f, a1 = 0.f, wacc = 0.f;
#pragma unroll
    for (int j = 0; j < 9; ++j) {
        const int c = jcnt[j];
        const unsigned* rb = recs + (size_t)jsrc[j] * cap * RECW;
        for (int i = q; i < c; i += 32) {
            const unsigned* r = rb + (size_t)i * RECW;
            const float w = __uint_as_float(r[16 + j]);  // broadcast in group
            const unsigned u = r[ch2];                   // 64B line per group
            a0   += w * __uint_as_float(u << 16);
            a1   += w * __uint_as_float(u & 0xFFFF0000u);
            wacc += w;
        }
    }

    red[q][2 * ch2]     = a0;
    red[q][2 * ch2 + 1] = a1;
    if (ch2 == 0) red[q][CCH] = wacc;
    __syncthreads();

    if (tid < CCH + 1) {
        float F = 0.f;
#pragma unroll
        for (int r = 0; r < 32; ++r) F += red[r][tid];
        F += ovf[(size_t)(b * K + k) * (CCH + 1) + tid];  // rare overflow
        red[0][tid] = F;   // red[0][0..31] = fsum, red[0][32] = wsum
    }
    __syncthreads();

    if (tid < CCH) {
        const float W   = red[0][CCH];
        const float res = (W > 1e-16f) ? (red[0][tid] / W) : 0.f;
        out[((size_t)b * CCH + tid) * K + k] = res;
    }
}

extern "C" void kernel_launch(void* const* d_in, const int* in_sizes, int n_in,
                              void* d_out, int out_size, void* d_ws, size_t ws_size,
                              hipStream_t stream) {
    const float* pf     = (const float*)d_in[0];
    const float* assoc  = (const float*)d_in[1];
    const int*   idxmap = (const int*)d_in[2];
    const int*   nw_p   = (const int*)d_in[3];
    const int*   nh_p   = (const int*)d_in[4];
    float* out = (float*)d_out;

    const int BP = in_sizes[2];          // B*P = 262144
    const int B  = 4;                    // fixed by reference setup
    const int P  = BP / B;               // 65536
    const int K  = out_size / (B * CCH); // 256 (== KMAX)

    // workspace: cnt [B*K int] | ovf [B*K*33 f32] | recs [B*K][cap][128B]
    const size_t cnt_bytes = (size_t)B * K * sizeof(int);
    const size_t ovf_bytes = (size_t)B * K * (CCH + 1) * sizeof(float);
    int*      cnt  = (int*)d_ws;
    float*    ovf  = (float*)((char*)d_ws + cnt_bytes);
    unsigned* recs = (unsigned*)((char*)d_ws + cnt_bytes + ovf_bytes);

    size_t avail = (ws_size > cnt_bytes + ovf_bytes)
                       ? (ws_size - cnt_bytes - ovf_bytes) : 0;
    int cap = (int)(avail / ((size_t)B * K * RECW * sizeof(unsigned)));
    if (cap > CAPC) cap = CAPC;
    if (cap < 1) cap = 1;

    hipMemsetAsync(cnt, 0, cnt_bytes + ovf_bytes, stream);  // cnt + ovf = 0

    const int bpb = P / PPB;             // 64 blocks per batch
    spx_prep_kernel<<<B * bpb, TPB, 0, stream>>>(
        pf, assoc, idxmap, nw_p, nh_p, cnt, recs, ovf, P, K, cap, bpb);

    spx_gather_kernel<<<B * K, GTPB, 0, stream>>>(
        recs, cnt, ovf, nw_p, nh_p, out, P, K, cap);
}